// Round 8
// baseline (1601.537 us; speedup 1.0000x reference)
//
#include <hip/hip_runtime.h>
#include <hip/hip_bf16.h>

// LTC RNN: B=512, T=1024, D=64, H=256, O=64.  32 blocks x 16 batch rows.
// R8: 4 waves x 64 j-cols (halves LDS A-frag reads: 80->40/step),
//     double-buffered A -> ONE barrier/step, native cvt for f32->bf16.
// R7 measured: 904us, MfmaUtil 3.7, VALUBusy 4.9, conflicts 0. Model: LDS-read
// port (960cyc/step) + serial epilogue tail. This attacks both.

typedef __attribute__((ext_vector_type(8))) short bf16x8;   // 8 bf16 (4 VGPRs)
typedef __attribute__((ext_vector_type(4))) short short4v;  // 8 B
typedef __attribute__((ext_vector_type(4))) float f32x4;

#define T_STEPS 1024
#define D_IN    64
#define H_DIM   256
#define O_DIM   64
#define ROWS    16
#define NTHREADS 256          // 4 waves, 1 per SIMD
#define LDS_STRIDE 640        // bytes per A-row: 320 bf16 = [x(64) | h(256)]
#define BUFSZ   (ROWS * LDS_STRIDE)   // 10240 B per buffer

__device__ __forceinline__ short f2bf(float x) {
    __hip_bfloat16 b = __float2bfloat16(x);      // native RNE cvt
    return *reinterpret_cast<short*>(&b);
}
__device__ __forceinline__ float sigm(float z) {
    float e = __builtin_amdgcn_exp2f(-1.4426950408889634f * z);   // exp(-z)
    return __builtin_amdgcn_rcpf(1.0f + e);
}

__global__ __launch_bounds__(NTHREADS, 1)
void ltc_kernel(const float* __restrict__ x_seq,  // [512,1024,64]
                const float* __restrict__ Wf,     // [256,320]
                const float* __restrict__ bf_,    // [256]
                const float* __restrict__ tau,    // [256]
                const float* __restrict__ Avec,   // [256]
                const float* __restrict__ Wo,     // [64,256]
                const float* __restrict__ bo,     // [64]
                float* __restrict__ out)          // [512,64] FLOAT32
{
    __shared__ alignas(64) char lds_raw[2 * BUFSZ];   // double-buffered A

    const int tid  = threadIdx.x;
    const int lane = tid & 63;
    const int w    = tid >> 6;        // wave 0..3
    const int lcol = lane & 15;
    const int lgrp = lane >> 4;       // 0..3
    const int brow0 = blockIdx.x * ROWS;
    const int jbase = w * 64;         // this wave's 64 j-columns (4 N-tiles)

    // ---------- Wf as B-fragments: lane supplies B[k][n=lcol] = Wf[j][k],
    // j = jbase + nt*16 + lcol (nt=0..3), k = kt*32 + lgrp*8 + e ----------
    bf16x8 bfrag[10][4];
    #pragma unroll
    for (int nt = 0; nt < 4; ++nt) {
        const int j = jbase + nt * 16 + lcol;
        const float* wrow = Wf + j * (D_IN + H_DIM);
        #pragma unroll
        for (int kt = 0; kt < 10; ++kt) {
            const int k0 = kt * 32 + lgrp * 8;
            f32x4 w0 = *(const f32x4*)(wrow + k0);
            f32x4 w1 = *(const f32x4*)(wrow + k0 + 4);
            bf16x8 b;
            b[0] = f2bf(w0[0]); b[1] = f2bf(w0[1]); b[2] = f2bf(w0[2]); b[3] = f2bf(w0[3]);
            b[4] = f2bf(w1[0]); b[5] = f2bf(w1[1]); b[6] = f2bf(w1[2]); b[7] = f2bf(w1[3]);
            bfrag[kt][nt] = b;
        }
    }

    // per-lane constants for the 4 j's this lane owns (C/D col = lane&15)
    const float dt = 0.1f;
    float bias[4], ctau[4], cA[4];
    #pragma unroll
    for (int nt = 0; nt < 4; ++nt) {
        const int j = jbase + nt * 16 + lcol;
        bias[nt] = bf_[j];
        ctau[nt] = 1.0f - dt * __builtin_amdgcn_rcpf(__expf(tau[j])); // 1 - dt/exp(tau)
        cA[nt]   = dt * Avec[j];
    }

    // ---------- zero both buffers (h0 = 0), stage x_0 into buf0 ----------
    for (int i = tid; i < (2 * BUFSZ) / 4; i += NTHREADS)
        ((unsigned*)lds_raw)[i] = 0u;
    __syncthreads();

    // x staging: 256 threads -> row = tid>>4 (16 rows), 4 floats at (tid&15)*4
    const int xrow = tid >> 4;
    const int xpos = tid & 15;
    const float* xbase = x_seq + ((size_t)(brow0 + xrow) * T_STEPS) * D_IN + xpos * 4;
    const int xbyte = xrow * LDS_STRIDE + ((xpos * 8) ^ ((xrow & 7) << 4));
    {
        f32x4 x0 = *(const f32x4*)(xbase);
        short4v xs = { f2bf(x0[0]), f2bf(x0[1]), f2bf(x0[2]), f2bf(x0[3]) };
        *(short4v*)(lds_raw + xbyte) = xs;   // buf0
    }
    __syncthreads();

    // A-frag reads: lane reads row m = lcol, k = kt*32 + lgrp*8 + e
    const int arow = lcol;
    const int abase_off = arow * LDS_STRIDE;
    const int aswz = (arow & 7) << 4;

    // h-write byte offsets (within a buffer), per nt (kbyte) and r (row m)
    int kbyte[4];
    #pragma unroll
    for (int nt = 0; nt < 4; ++nt) kbyte[nt] = 2 * D_IN + 2 * (jbase + nt * 16 + lcol);

    // fp32 master state: h[nt][r] at (row m = lgrp*4+r, col j = jbase+nt*16+lcol)
    float h[4][4] = {};

    int p = 0;   // read-buffer parity
    for (int t = 0; t < T_STEPS; ++t) {
        const char* rbuf = lds_raw + p * BUFSZ;
        char*       wbuf = lds_raw + (p ^ 1) * BUFSZ;

        // prefetch x_{t+1} (global; hides under MFMA + epilogue)
        const int tn = (t + 1 < T_STEPS) ? (t + 1) : (T_STEPS - 1);
        f32x4 xv = *(const f32x4*)(xbase + (size_t)tn * D_IN);

        // read A fragments for step t
        bf16x8 afrag[10];
        #pragma unroll
        for (int kt = 0; kt < 10; ++kt) {
            const int off = (kt * 64 + lgrp * 16) ^ aswz;
            afrag[kt] = *(const bf16x8*)(rbuf + abase_off + off);
        }

        // z = bias + inp @ Wf^T  (4 independent acc chains, kt-outer interleave)
        f32x4 acc[4];
        #pragma unroll
        for (int nt = 0; nt < 4; ++nt)
            acc[nt] = f32x4{ bias[nt], bias[nt], bias[nt], bias[nt] };
        #pragma unroll
        for (int kt = 0; kt < 10; ++kt) {
            #pragma unroll
            for (int nt = 0; nt < 4; ++nt)
                acc[nt] = __builtin_amdgcn_mfma_f32_16x16x32_bf16(afrag[kt], bfrag[kt][nt], acc[nt], 0, 0, 0);
        }

        // epilogue: f = sigmoid(z); h = h*(ctau - dt*f) + (dt*A)*f
        short hb[4][4];
        #pragma unroll
        for (int nt = 0; nt < 4; ++nt) {
            #pragma unroll
            for (int r = 0; r < 4; ++r) {
                float f = sigm(acc[nt][r]);
                h[nt][r] = h[nt][r] * (ctau[nt] - dt * f) + cA[nt] * f;
                hb[nt][r] = f2bf(h[nt][r]);
            }
        }

        // write h_{t+1} into the OTHER buffer (no barrier needed before writes)
        #pragma unroll
        for (int r = 0; r < 4; ++r) {
            const int m = lgrp * 4 + r;
            const int mrow = m * LDS_STRIDE;
            const int msw = (m & 7) << 4;
            #pragma unroll
            for (int nt = 0; nt < 4; ++nt)
                *(short*)(wbuf + mrow + (kbyte[nt] ^ msw)) = hb[nt][r];
        }
        // stage x_{t+1} into the other buffer
        {
            short4v xs = { f2bf(xv[0]), f2bf(xv[1]), f2bf(xv[2]), f2bf(xv[3]) };
            *(short4v*)(wbuf + xbyte) = xs;
        }

        __syncthreads();   // single barrier: everyone done writing buf[p^1]
        p ^= 1;
    }

    // ---------- out = h_T @ Wo^T + bo ; h_T (bf16) in buf0 (T even) ----------
    {
        const char* fbuf = lds_raw;   // p ended at 0
        bf16x8 ha[8];
        #pragma unroll
        for (int kt = 0; kt < 8; ++kt) {
            const int off = (2 * D_IN + kt * 64 + lgrp * 16) ^ aswz;
            ha[kt] = *(const bf16x8*)(fbuf + abase_off + off);
        }
        const int o = w * 16 + lcol;              // lane supplies Wo[o][k]; C/D col -> same o
        const float* worow = Wo + o * H_DIM;
        const float bov = bo[o];
        f32x4 acc = { bov, bov, bov, bov };
        #pragma unroll
        for (int kt = 0; kt < 8; ++kt) {
            const int k0 = kt * 32 + lgrp * 8;
            f32x4 w0 = *(const f32x4*)(worow + k0);
            f32x4 w1 = *(const f32x4*)(worow + k0 + 4);
            bf16x8 b;
            b[0] = f2bf(w0[0]); b[1] = f2bf(w0[1]); b[2] = f2bf(w0[2]); b[3] = f2bf(w0[3]);
            b[4] = f2bf(w1[0]); b[5] = f2bf(w1[1]); b[6] = f2bf(w1[2]); b[7] = f2bf(w1[3]);
            acc = __builtin_amdgcn_mfma_f32_16x16x32_bf16(ha[kt], b, acc, 0, 0, 0);
        }
        #pragma unroll
        for (int r = 0; r < 4; ++r) {
            const int m = lgrp * 4 + r;           // C/D row = (lane>>4)*4 + reg
            out[(size_t)(brow0 + m) * O_DIM + o] = acc[r];
        }
    }
}

extern "C" void kernel_launch(void* const* d_in, const int* in_sizes, int n_in,
                              void* d_out, int out_size, void* d_ws, size_t ws_size,
                              hipStream_t stream) {
    const float* x_seq = (const float*)d_in[0];
    const float* Wf    = (const float*)d_in[1];
    const float* bf_   = (const float*)d_in[2];
    const float* tau   = (const float*)d_in[3];
    const float* Avec  = (const float*)d_in[4];
    const float* Wo    = (const float*)d_in[5];
    const float* bo    = (const float*)d_in[6];
    float* out = (float*)d_out;   // reference output dtype is float32

    ltc_kernel<<<512 / ROWS, NTHREADS, 0, stream>>>(x_seq, Wf, bf_, tau, Avec, Wo, bo, out);
}